// Round 9
// baseline (179.469 us; speedup 1.0000x reference)
//
#include <hip/hip_runtime.h>
#include <math.h>

// RC thermal model: x' = A x + b0*To(t) + Bq, RK4 h=30, T=1e6 steps.
// Per step: x_{t+1} = M x_t + c + al*To[t] + be*To[t+1].
// R9: (1) single-pass decoupled-lookback scan: one heavy kernel. Blocks
// take a ticket (atomicAdd -> deadlock-free ordering), publish their
// 1024-step aggregate with device-scope atomics + release flag, spin-wait
// (acquire, bounded) on <=64 predecessors (M^65536 ~ 3e-9 truncation).
// Lookback/prefix/expand math is R8's (passed, absmax 4.0).
// (2) setup cut from ~46 to ~21 single-barrier rounds: 15-squaring chain
// (sequential, unavoidable) + Pd[0..15] via 2 parallel product rounds
// Pd[j] = Qhi[j>>2]*Qlo[j&3] instead of the 14-round serial Pd chain.

#define S_STEPS 999999
#define CH      4
#define BLK     256
#define NB      977          // 977*256*4 = 1,000,448 >= S_STEPS
#define NCHUNK  250000       // active chunks (last partial: 3 steps)
#define LASTFULL 249998      // g <= LASTFULL: To[4g+4] in bounds

// ws float offsets
#define OFF_M   0            // 144: M
#define OFF_C   144          // 12
#define OFF_AL  156          // 12
#define OFF_BE  168          // 12
#define OFF_K   192          // 72: K cols [col][12], col0 = const
#define OFF_P2  264          // 8*144: P2[l] = M^(4*2^l), l=0..7 (M^4..M^512)
#define OFF_PA  1416         // 144: M^768
#define OFF_PL  1560         // 3*144: M^1024, M^2048, M^3072
#define OFF_PD  1992         // 16*144: M^(4096j), j=0..15 (Pd[0]=I)
#define OFF_CNT 4296         // 1 int: ticket counter
#define OFF_FLG 4300         // NB ints: publish flags
#define OFF_AGG 5280         // NB*12 block aggregates

#define FMA4(Q,a,b,c,d,acc) fmaf((Q).w,(d),fmaf((Q).z,(c),fmaf((Q).y,(b),fmaf((Q).x,(a),(acc)))))

// y += P(12x12 row-major, 16B-aligned) * x
__device__ __forceinline__ void mv_acc(const float* Pf, const float* x, float* y) {
  const float4* P = reinterpret_cast<const float4*>(Pf);
#pragma unroll
  for (int i = 0; i < 12; ++i) {
    float4 a = P[3*i], b = P[3*i+1], c = P[3*i+2];
    y[i] = FMA4(c, x[8],x[9],x[10],x[11],
            FMA4(b, x[4],x[5],x[6],x[7],
             FMA4(a, x[0],x[1],x[2],x[3], y[i])));
  }
}

__device__ __forceinline__ float rowdot(const float* Prow, const float* xv) {
  const float4* P = reinterpret_cast<const float4*>(Prow);
  float4 a = P[0], b = P[1], c = P[2];
  return FMA4(c, xv[8],xv[9],xv[10],xv[11],
          FMA4(b, xv[4],xv[5],xv[6],xv[7],
           FMA4(a, xv[0],xv[1],xv[2],xv[3], 0.f)));
}

// v = K[:,0] + sum_{s=0..4} K[:,s+1]*tos[s]
__device__ __forceinline__ void fold_chunk(const float* __restrict__ cons,
                                           const float* tos, float* v) {
  const float4* Kq = reinterpret_cast<const float4*>(cons + OFF_K);
  float4 c0=Kq[0], c1=Kq[1], c2=Kq[2];
  v[0]=c0.x; v[1]=c0.y; v[2]=c0.z; v[3]=c0.w;
  v[4]=c1.x; v[5]=c1.y; v[6]=c1.z; v[7]=c1.w;
  v[8]=c2.x; v[9]=c2.y; v[10]=c2.z; v[11]=c2.w;
#pragma unroll
  for (int s = 0; s < 5; ++s) {
    float ts = tos[s];
    float4 ka=Kq[3*(s+1)], kb=Kq[3*(s+1)+1], kc=Kq[3*(s+1)+2];
    v[0]=fmaf(ka.x,ts,v[0]); v[1]=fmaf(ka.y,ts,v[1]); v[2]=fmaf(ka.z,ts,v[2]); v[3]=fmaf(ka.w,ts,v[3]);
    v[4]=fmaf(kb.x,ts,v[4]); v[5]=fmaf(kb.y,ts,v[5]); v[6]=fmaf(kb.z,ts,v[6]); v[7]=fmaf(kb.w,ts,v[7]);
    v[8]=fmaf(kc.x,ts,v[8]); v[9]=fmaf(kc.y,ts,v[9]); v[10]=fmaf(kc.z,ts,v[10]); v[11]=fmaf(kc.w,ts,v[11]);
  }
}

__global__ void __launch_bounds__(512) setup_kernel(
    const float* __restrict__ t_eval, const float* __restrict__ A,
    const float* __restrict__ Bm, const float* __restrict__ loads_raw,
    const float* __restrict__ areas, float* ws) {
  __shared__ double H1[144], H2[144], H3[144], H4[144], Md[144];
  __shared__ double Qa[144], Qb[144];
  __shared__ double C256[144], C512[144], C1024[144], C2048[144];
  __shared__ double C4096[144], C8192[144], C16384[144], C32768[144];
  __shared__ double C12288[144], C49152[144];
  __shared__ double cd[12], ald[12], bed[12], b0d[12], bqd[12];
  __shared__ double Vv[2][3][12], Kd[72];
  int t = threadIdx.x;
  double h = (double)t_eval[1] - (double)t_eval[0];
  if (t < 144) H1[t] = h * (double)A[t];
  if (t < 12) {
    b0d[t] = (double)Bm[t*11];
    double s = 0.0;
    for (int r = 0; r < 10; ++r) {
      double gq = 50.0 / (1.0 + exp(-(double)loads_raw[10 + r]));
      s += (double)Bm[t*11 + 1 + r] * (gq * (double)areas[r]);
    }
    bqd[t] = s;
  }
  if (t < 72) Kd[t] = 0.0;
  {                                           // zero ticket counter + flags
    int* wsi = (int*)ws;
    for (int idx = t; idx < NB + 4; idx += 512) wsi[OFF_CNT + idx] = 0;
  }
  __syncthreads();
  if (t < 144) {                              // H2 = H1*H1
    int i=t/12, j=t%12; double s=0.0;
#pragma unroll
    for (int m = 0; m < 12; ++m) s += H1[i*12+m]*H1[m*12+j];
    H2[t]=s;
  }
  __syncthreads();
  if (t < 288) {                              // H3 = H2*H1 | H4 = H2*H2
    int w=t/144, e=t%144, i=e/12, j=e%12;
    const double* Bp = w ? H2 : H1;
    double s = 0.0;
#pragma unroll
    for (int m = 0; m < 12; ++m) s += H2[i*12+m]*Bp[m*12+j];
    (w ? H4 : H3)[e] = s;
  }
  __syncthreads();
  if (t < 12) {                               // consts + Vv[0] + K it=0
    double hb=0,h2b=0,h3b=0,hb0=0,h2b0=0,h3b0=0;
#pragma unroll
    for (int m = 0; m < 12; ++m) {
      hb  += H1[t*12+m]*bqd[m]; h2b  += H2[t*12+m]*bqd[m]; h3b  += H3[t*12+m]*bqd[m];
      hb0 += H1[t*12+m]*b0d[m]; h2b0 += H2[t*12+m]*b0d[m]; h3b0 += H3[t*12+m]*b0d[m];
    }
    double h6 = h / 6.0;
    cd[t]  = h6*(6.0*bqd[t] + 3.0*hb + h2b + 0.25*h3b);
    ald[t] = h6*(3.0*b0d[t] + 2.0*hb0 + 0.75*h2b0 + 0.25*h3b0);
    bed[t] = h6*(3.0*b0d[t] + hb0 + 0.25*h2b0);
    Vv[0][0][t]=ald[t]; Vv[0][1][t]=bed[t]; Vv[0][2][t]=cd[t];
    Kd[48+t] += ald[t]; Kd[60+t] += bed[t]; Kd[t] += cd[t];
  }
  if (t >= 144 && t < 288) {                  // Md = RK4 one-step matrix
    int e=t-144, i=e/12, j=e%12;
    Md[e] = (i==j ? 1.0 : 0.0) + H1[e] + 0.5*H2[e] + H3[e]/6.0 + H4[e]/24.0;
  }
  __syncthreads();
  // chain r=1..15: M^(2^r), single barrier per round. K overlap r=1..3
  // (Vv ping-pong). r==1 spare threads write M/C/AL/BE floats to ws.
  for (int r = 1; r <= 15; ++r) {
    const double* src = (r==1) ? Md : ((r & 1) ? Qb : Qa);
    double* dst = (r & 1) ? Qa : Qb;
    double acc = 0.0, ks = 0.0;
    if (t < 144) {
      int i=t/12, j=t%12;
#pragma unroll
      for (int m = 0; m < 12; ++m) acc += src[i*12+m]*src[m*12+j];
    }
    int w=0, i2=0;
    if (r <= 3 && t >= 256 && t < 292) {
      w=(t-256)/12; i2=(t-256)%12;
#pragma unroll
      for (int m = 0; m < 12; ++m) ks += Md[i2*12+m]*Vv[(r+1)&1][w][m];
    }
    if (r == 1) {
      if (t >= 300 && t < 444) ws[OFF_M + (t-300)] = (float)Md[t-300];
      if (t >= 444 && t < 456) {
        int i = t-444;
        ws[OFF_C+i]=(float)cd[i]; ws[OFF_AL+i]=(float)ald[i]; ws[OFF_BE+i]=(float)bed[i];
      }
    }
    if (t < 144) {
      dst[t] = acc;
      if (r >= 2 && r <= 9)  ws[OFF_P2 + (r-2)*144 + t] = (float)acc;
      if (r == 8)  C256[t] = acc;
      if (r == 9)  C512[t] = acc;
      if (r == 10) { C1024[t] = acc; ws[OFF_PL + t] = (float)acc; }
      if (r == 11) { C2048[t] = acc; ws[OFF_PL + 144 + t] = (float)acc; }
      if (r == 12) C4096[t] = acc;
      if (r == 13) C8192[t] = acc;
      if (r == 14) C16384[t] = acc;
      if (r == 15) C32768[t] = acc;
    }
    if (r <= 3 && t >= 256 && t < 292) {
      Vv[r&1][w][i2] = ks;
      if (w == 0) Kd[(4-r)*12+i2] += ks;
      else if (w == 1) Kd[(5-r)*12+i2] += ks;
      else Kd[i2] += ks;
    }
    __syncthreads();
  }
  if (t < 72) ws[OFF_K + t] = (float)Kd[t];
  if (t < 144) {                              // direct Pd entries
    ws[OFF_PD + t]         = (t % 13 == 0) ? 1.f : 0.f;
    ws[OFF_PD + 144 + t]   = (float)C4096[t];
    ws[OFF_PD + 2*144 + t] = (float)C8192[t];
    ws[OFF_PD + 4*144 + t] = (float)C16384[t];
    ws[OFF_PD + 8*144 + t] = (float)C32768[t];
  }
  // product round A (parallel): M^768, M^3072, M^12288, M^49152
  for (int idx = t; idx < 576; idx += 512) {
    int p = idx / 144, e = idx - p*144, i = e/12, jj = e - i*12;
    const double* Ap = (p==0)?C256:(p==1)?C1024:(p==2)?C4096:C16384;
    const double* Bp = (p==0)?C512:(p==1)?C2048:(p==2)?C8192:C32768;
    double s = 0.0;
#pragma unroll
    for (int m = 0; m < 12; ++m) s += Ap[i*12+m]*Bp[m*12+jj];
    if (p==0) ws[OFF_PA + e] = (float)s;
    else if (p==1) ws[OFF_PL + 2*144 + e] = (float)s;
    else if (p==2) { C12288[e] = s; ws[OFF_PD + 3*144 + e] = (float)s; }
    else { C49152[e] = s; ws[OFF_PD + 12*144 + e] = (float)s; }
  }
  __syncthreads();
  // product round B: remaining Pd[j] = Qhi[j>>2]*Qlo[j&3]
  const int jl[9] = {5,6,7,9,10,11,13,14,15};
  for (int idx = t; idx < 1296; idx += 512) {
    int q = idx / 144, e = idx - q*144, i = e/12, jj = e - i*12;
    int j = jl[q];
    int hi = j >> 2, lo = j & 3;
    const double* Hp = (hi==1)?C16384:(hi==2)?C32768:C49152;
    const double* Lp = (lo==1)?C4096:(lo==2)?C8192:C12288;
    double s = 0.0;
#pragma unroll
    for (int m = 0; m < 12; ++m) s += Hp[i*12+m]*Lp[m*12+jj];
    ws[OFF_PD + j*144 + e] = (float)s;
  }
}

// Single-pass scan: fold + wave shfl-scan + early aggregate publish
// (release flag) + truncated 64-block decoupled lookback (acquire spin)
// + Pw/Qw prefix + per-thread M^(4j) apply + 4-step expand.
__global__ void __launch_bounds__(BLK, 4) fused_scan(
    const float* __restrict__ cons, const float* __restrict__ To,
    const float* __restrict__ x0, float* agg, int* flags, int* cnt,
    float* __restrict__ out) {
  __shared__ int sbid;
  __shared__ __align__(16) float Tw[48], Ta[24], Pw[48];
  __shared__ __align__(16) float aggL[64*12];
  __shared__ __align__(16) float lkb[64*12];
  __shared__ __align__(16) float yv[192], zv[192], Xs[12], Qw[48];
  int k = threadIdx.x;
  if (k == 0) sbid = atomicAdd(cnt, 1);       // ticket = deadlock-free order
  __syncthreads();
  int b = sbid;
  int g = b*BLK + k, base = g*CH;
  bool active = (g < NCHUNK), fullc = (g <= LASTFULL);
  float to_[5];
#pragma unroll
  for (int i = 0; i < 5; ++i) to_[i] = 0.f;
  if (active) {
    const float4* tp = reinterpret_cast<const float4*>(To + base);
    float4 ta = tp[0];
    to_[0]=ta.x; to_[1]=ta.y; to_[2]=ta.z; to_[3]=ta.w;
    to_[4] = fullc ? To[base+4] : 0.f;
  }
  float v[12];
  if (fullc) fold_chunk(cons, to_, v);
  else {
#pragma unroll
    for (int i = 0; i < 12; ++i) v[i] = 0.f;
  }
  if (g == 0) {                               // fold x0: v += M^4 x0
    float xi[12];
#pragma unroll
    for (int i = 0; i < 12; ++i) xi[i] = x0[i];
    mv_acc(cons + OFF_P2, xi, v);
  }
  int j = k & 63, w = k >> 6;
#pragma unroll
  for (int l = 0; l < 6; ++l) {               // in-wave inclusive scan
    int off = 1 << l;
    float nb[12];
#pragma unroll
    for (int i = 0; i < 12; ++i) nb[i] = __shfl_up(v[i], (unsigned)off, 64);
    if (j >= off) mv_acc(cons + OFF_P2 + l*144, nb, v);
  }
  float se[12];                               // exclusive in-wave scan
#pragma unroll
  for (int i = 0; i < 12; ++i) {
    float u = __shfl_up(v[i], 1u, 64);
    se[i] = (j == 0) ? 0.f : u;
  }
  if (j == 63) {
#pragma unroll
    for (int i = 0; i < 12; ++i) Tw[w*12 + i] = v[i];
  }
  __syncthreads();
  // round 1: Ta pairs (M^256 combine) | Pw0=0, Pw1=T0
  if (k < 24) {
    int p = k/12, comp = k - p*12;
    Ta[k] = rowdot(cons + OFF_P2 + 6*144 + comp*12, Tw + 2*p*12)
          + Tw[(2*p+1)*12 + comp];
  } else if (k < 48) {
    int q = k - 24;
    if (q < 12) Pw[q] = 0.f;
    else Pw[q] = Tw[q-12];
  }
  __syncthreads();
  // round 2: publish agg (M^512 combine, device-scope stores) | Pw2
  if (k < 12) {
    float val = rowdot(cons + OFF_P2 + 7*144 + k*12, Ta) + Ta[12 + k];
    __hip_atomic_store(&agg[b*12 + k], val, __ATOMIC_RELAXED,
                       __HIP_MEMORY_SCOPE_AGENT);
  } else if (k >= 192 && k < 204) {
    int comp = k - 192;
    Pw[24+comp] = rowdot(cons + OFF_P2 + 6*144 + comp*12, Pw+12) + Tw[12+comp];
  }
  __syncthreads();                            // agg stores drained (vmcnt)
  // round 3: release flag | spin-acquire predecessors -> aggL | Pw3
  if (k == 0) {
    __threadfence();
    __hip_atomic_store(&flags[b], 1, __ATOMIC_RELEASE, __HIP_MEMORY_SCOPE_AGENT);
  } else if (k >= 64 && k < 128) {
    int slot = k - 64, src = b - 1 - slot;
    if (src >= 0) {
      int guard = 0;
      while (__hip_atomic_load(&flags[src], __ATOMIC_ACQUIRE,
                               __HIP_MEMORY_SCOPE_AGENT) == 0 &&
             guard < (1<<20)) {
        ++guard;
        __builtin_amdgcn_s_sleep(2);
      }
#pragma unroll
      for (int i = 0; i < 12; ++i)
        aggL[slot*12 + i] = __hip_atomic_load(&agg[src*12 + i],
                                              __ATOMIC_RELAXED,
                                              __HIP_MEMORY_SCOPE_AGENT);
    } else {
#pragma unroll
      for (int i = 0; i < 12; ++i) aggL[slot*12 + i] = 0.f;
    }
  } else if (k >= 192 && k < 204) {
    int comp = k - 192;
    Pw[36+comp] = rowdot(cons + OFF_P2 + 6*144 + comp*12, Pw+24) + Tw[24+comp];
  }
  __syncthreads();
  // lookback stage 1: lkb[slot] = M^(1024*(slot&3)) * aggL[slot]
#pragma unroll
  for (int r = 0; r < 3; ++r) {
    int idx = k + r*BLK;
    int slot = idx / 12, comp = idx - slot*12, jj = slot & 3;
    lkb[idx] = (jj == 0) ? aggL[slot*12 + comp]
             : rowdot(cons + OFF_PL + (jj-1)*144 + comp*12, aggL + slot*12);
  }
  __syncthreads();
  if (k < 192) {                              // yv[i] = sum_jj lkb[4i+jj]
    int i = k/12, comp = k - i*12;
    yv[k] = lkb[(4*i)*12+comp] + lkb[(4*i+1)*12+comp]
          + lkb[(4*i+2)*12+comp] + lkb[(4*i+3)*12+comp];
  }
  __syncthreads();
  if (k < 192) {                              // zv[i] = M^(4096i)*yv[i]
    int i = k/12, comp = k - i*12;
    zv[k] = (i == 0) ? yv[k]
          : rowdot(cons + OFF_PD + i*144 + comp*12, yv + i*12);
  }
  __syncthreads();
  if (k < 12) {                               // Xs = sum_i zv[i]
    float s = 0.f;
#pragma unroll
    for (int i = 0; i < 16; ++i) s += zv[i*12 + k];
    Xs[k] = s;
  }
  __syncthreads();
  // Qw[w] = M^(256w)*Xs + Pw[w]
  if (k < 48) {
    int ww = k/12, comp = k - ww*12;
    float acc;
    if (ww == 0) acc = Xs[comp];
    else if (ww == 1) acc = rowdot(cons + OFF_P2 + 6*144 + comp*12, Xs);
    else if (ww == 2) acc = rowdot(cons + OFF_P2 + 7*144 + comp*12, Xs);
    else acc = rowdot(cons + OFF_PA + comp*12, Xs);
    Qw[k] = acc + Pw[k];
  }
  __syncthreads();
  if (!active) return;                        // all barriers done
  // per-thread: x = M^(4j)*Qw[w] + se
  float x[12];
#pragma unroll
  for (int i = 0; i < 12; ++i) x[i] = Qw[w*12 + i];
#pragma unroll
  for (int l = 0; l < 6; ++l) {
    if ((j >> l) & 1) {
      float vn[12];
#pragma unroll
      for (int i = 0; i < 12; ++i) vn[i] = 0.f;
      mv_acc(cons + OFF_P2 + l*144, x, vn);
#pragma unroll
      for (int i = 0; i < 12; ++i) x[i] = vn[i];
    }
  }
#pragma unroll
  for (int i = 0; i < 12; ++i) x[i] += se[i];
  if (b == 0 && k == 0) {
#pragma unroll
    for (int i = 0; i < 12; ++i) x[i] += x0[i];
#pragma unroll
    for (int i = 0; i < 12; ++i) out[i] = x0[i];       // row 0
  }
  // expand: 4 unconditional steps, predicated stores (no break)
  float cv[12], av[12], bv[12];
#pragma unroll
  for (int i = 0; i < 12; ++i) {
    cv[i] = cons[OFF_C + i]; av[i] = cons[OFF_AL + i]; bv[i] = cons[OFF_BE + i];
  }
  const float4* Mq = reinterpret_cast<const float4*>(cons + OFF_M);
#pragma unroll
  for (int s = 0; s < CH; ++s) {
    float tot = to_[s], ton = (s < CH-1) ? to_[s+1] : to_[4];
    float xn[12];
#pragma unroll
    for (int i = 0; i < 12; ++i) {
      float4 a = Mq[3*i], bq = Mq[3*i+1], c = Mq[3*i+2];
      xn[i] = FMA4(c, x[8],x[9],x[10],x[11],
               FMA4(bq, x[4],x[5],x[6],x[7],
                FMA4(a, x[0],x[1],x[2],x[3],
                 fmaf(bv[i],ton,fmaf(av[i],tot,cv[i])))));
    }
    int tt = base + s;
    if (tt < S_STEPS) {
      float4* op = reinterpret_cast<float4*>(out + (size_t)(tt+1)*12);
      op[0] = make_float4(xn[0],xn[1],xn[2],xn[3]);
      op[1] = make_float4(xn[4],xn[5],xn[6],xn[7]);
      op[2] = make_float4(xn[8],xn[9],xn[10],xn[11]);
    }
#pragma unroll
    for (int i = 0; i < 12; ++i) x[i] = xn[i];
  }
}

extern "C" void kernel_launch(void* const* d_in, const int* in_sizes, int n_in,
                              void* d_out, int out_size, void* d_ws, size_t ws_size,
                              hipStream_t stream) {
  const float* t_eval    = (const float*)d_in[0];
  const float* x0        = (const float*)d_in[1];
  const float* A         = (const float*)d_in[2];
  const float* B         = (const float*)d_in[3];
  const float* To        = (const float*)d_in[4];
  const float* loads_raw = (const float*)d_in[5];
  const float* areas     = (const float*)d_in[6];
  float* out = (float*)d_out;
  float* ws  = (float*)d_ws;
  int*   wsi = (int*)d_ws;

  setup_kernel<<<1, 512, 0, stream>>>(t_eval, A, B, loads_raw, areas, ws);
  fused_scan<<<NB, BLK, 0, stream>>>(ws, To, x0, ws + OFF_AGG,
                                     wsi + OFF_FLG, wsi + OFF_CNT, out);
}